// Round 1
// baseline (394.258 us; speedup 1.0000x reference)
//
#include <hip/hip_runtime.h>
#include <hip/hip_bf16.h>
#include <stdint.h>

typedef __attribute__((ext_vector_type(8))) __bf16 bf16x8;
typedef __attribute__((ext_vector_type(4))) float f32x4;
typedef __attribute__((ext_vector_type(4))) unsigned int u32x4;

#define HIDDEN 1024
#define HEADS 16
#define HD 64
#define NB 4
#define T_ 2048
#define M_ROWS (NB * T_)  // 8192

__device__ __forceinline__ unsigned short f2bf(float x) {
  unsigned u = __builtin_bit_cast(unsigned, x);
  u += 0x7fff + ((u >> 16) & 1);
  return (unsigned short)(u >> 16);
}

__device__ __forceinline__ f32x4 mfma_bf16(bf16x8 a, bf16x8 b, f32x4 c) {
  return __builtin_amdgcn_mfma_f32_16x16x32_bf16(a, b, c, 0, 0, 0);
}

__device__ __forceinline__ void lds16(const void* g, void* l) {
  __builtin_amdgcn_global_load_lds(
      (const __attribute__((address_space(1))) unsigned int*)g,
      (__attribute__((address_space(3))) unsigned int*)l, 16, 0, 0);
}

__device__ __forceinline__ bf16x8 ldg8(const unsigned short* p) {
  return __builtin_bit_cast(bf16x8, *(const u32x4*)p);
}

// ---------------- f32 -> bf16 convert ----------------
__global__ void cvt_bf16(const float* __restrict__ in,
                         unsigned short* __restrict__ out, int n4) {
  int i = blockIdx.x * blockDim.x + threadIdx.x;
  int stride = gridDim.x * blockDim.x;
  for (; i < n4; i += stride) {
    float4 v = ((const float4*)in)[i];
    ushort4 o;
    o.x = f2bf(v.x); o.y = f2bf(v.y); o.z = f2bf(v.z); o.w = f2bf(v.w);
    ((ushort4*)out)[i] = o;
  }
}

// ---------------- 128x128 MFMA GEMM, C = A * B^T (+bias), m97 structure ----
// A: [M][K] bf16 row-major; Bm: [N][K] bf16 row-major (torch (out,in) layout)
// EPI 0: scatter QKV -> Q[B,H,T,D], K[B,H,T,D], Vt[B,H,D,T] (bf16, +bias)
// EPI 1: Cf[M][N] f32 = acc + bias
template <int EPI>
__global__ __launch_bounds__(256) void gemm_bt(
    const unsigned short* __restrict__ A, const unsigned short* __restrict__ Bm,
    const float* __restrict__ bias, unsigned short* __restrict__ Qb,
    unsigned short* __restrict__ Kb, unsigned short* __restrict__ Vtb,
    float* __restrict__ Cf, int M, int N, int K) {
  __shared__ __align__(16) unsigned short Al[128 * 32];
  __shared__ __align__(16) unsigned short Bl[128 * 32];
  const int tid = threadIdx.x;
  const int w = tid >> 6, lane = tid & 63;
  const int l16 = lane & 15, grp = lane >> 4;
  const int brow0 = blockIdx.y * 128;
  const int bcol0 = blockIdx.x * 128;
  const int wrow = (w >> 1) * 64, wcol = (w & 1) * 64;

  f32x4 acc[4][4];
#pragma unroll
  for (int i = 0; i < 4; i++)
#pragma unroll
    for (int j = 0; j < 4; j++) acc[i][j] = (f32x4){0.f, 0.f, 0.f, 0.f};

  for (int k0 = 0; k0 < K; k0 += 32) {
    __syncthreads();
#pragma unroll
    for (int i = 0; i < 2; i++) {
      int off = (w * 2 + i) * 1024 + lane * 16;  // byte offset in 8KB tile
      int row = off >> 6;
      int cole = (off & 63) >> 1;  // element column within BK=32
      lds16(A + (size_t)(brow0 + row) * K + k0 + cole,
            (char*)Al + (w * 2 + i) * 1024);
      lds16(Bm + (size_t)(bcol0 + row) * K + k0 + cole,
            (char*)Bl + (w * 2 + i) * 1024);
    }
    __syncthreads();
    bf16x8 av[4], bv[4];
#pragma unroll
    for (int m = 0; m < 4; m++)
      av[m] = __builtin_bit_cast(
          bf16x8, *(const u32x4*)&Al[(wrow + m * 16 + l16) * 32 + grp * 8]);
#pragma unroll
    for (int n = 0; n < 4; n++)
      bv[n] = __builtin_bit_cast(
          bf16x8, *(const u32x4*)&Bl[(wcol + n * 16 + l16) * 32 + grp * 8]);
#pragma unroll
    for (int m = 0; m < 4; m++)
#pragma unroll
      for (int n = 0; n < 4; n++) acc[m][n] = mfma_bf16(av[m], bv[n], acc[m][n]);
  }

#pragma unroll
  for (int m = 0; m < 4; m++) {
#pragma unroll
    for (int n = 0; n < 4; n++) {
      int col = bcol0 + wcol + n * 16 + l16;
      int row0 = brow0 + wrow + m * 16 + grp * 4;
      float bs = bias[col];
      if (EPI == 0) {
        int part = col >> 10, rem = col & 1023;
        int h = rem >> 6, d = rem & 63;
#pragma unroll
        for (int r = 0; r < 4; r++) {
          int rw = row0 + r;
          int b = rw >> 11, t = rw & 2047;
          unsigned short val = f2bf(acc[m][n][r] + bs);
          size_t bh = (size_t)(b * 16 + h);
          if (part == 0)
            Qb[(bh * T_ + t) * HD + d] = val;
          else if (part == 1)
            Kb[(bh * T_ + t) * HD + d] = val;
          else
            Vtb[(bh * HD + d) * T_ + t] = val;
        }
      } else {
#pragma unroll
        for (int r = 0; r < 4; r++)
          Cf[(size_t)(row0 + r) * N + col] = acc[m][n][r] + bs;
      }
    }
  }
}

// ---------------- causal flash attention ----------------
// grid: x = B*H (64), y = T/64 (32).  block: 256 = 4 waves, 16 q-rows/wave.
__global__ __launch_bounds__(256) void attn_kernel(
    const unsigned short* __restrict__ Q, const unsigned short* __restrict__ K,
    const unsigned short* __restrict__ Vt, unsigned short* __restrict__ Ao) {
  __shared__ __align__(16) unsigned short Pl[4][16 * 40];  // +8 pad: bank-safe
  const int bh = blockIdx.x;
  const int q0 = ((int)gridDim.y - 1 - (int)blockIdx.y) * 64;  // heavy q first
  const int w = threadIdx.x >> 6, lane = threadIdx.x & 63;
  const int l16 = lane & 15, grp = lane >> 4;
  const unsigned short* Qh = Q + (size_t)bh * T_ * HD;
  const unsigned short* Kh = K + (size_t)bh * T_ * HD;
  const unsigned short* Vh = Vt + (size_t)bh * HD * T_;
  const int qrBase = q0 + w * 16;

  bf16x8 qf[2];
#pragma unroll
  for (int c = 0; c < 2; c++)
    qf[c] = ldg8(&Qh[(size_t)(qrBase + l16) * HD + c * 32 + grp * 8]);

  f32x4 o[4];
  float m[4], l[4];
#pragma unroll
  for (int dc = 0; dc < 4; dc++) o[dc] = (f32x4){0.f, 0.f, 0.f, 0.f};
#pragma unroll
  for (int r = 0; r < 4; r++) { m[r] = -1e30f; l[r] = 0.f; }
  const float SCL = 0.125f;  // 1/sqrt(64)
  const int nch = ((qrBase + 15) >> 5) + 1;

  for (int kc = 0; kc < nch; kc++) {
    const int kt = kc * 32;
    bf16x8 kf00 = ldg8(&Kh[(size_t)(kt + l16) * HD + grp * 8]);
    bf16x8 kf01 = ldg8(&Kh[(size_t)(kt + l16) * HD + 32 + grp * 8]);
    bf16x8 kf10 = ldg8(&Kh[(size_t)(kt + 16 + l16) * HD + grp * 8]);
    bf16x8 kf11 = ldg8(&Kh[(size_t)(kt + 16 + l16) * HD + 32 + grp * 8]);
    bf16x8 vf[4];
#pragma unroll
    for (int dc = 0; dc < 4; dc++)
      vf[dc] = ldg8(&Vh[(size_t)(dc * 16 + l16) * T_ + kt + grp * 8]);

    f32x4 s0 = {0.f, 0.f, 0.f, 0.f}, s1 = {0.f, 0.f, 0.f, 0.f};
    s0 = mfma_bf16(qf[0], kf00, s0);
    s0 = mfma_bf16(qf[1], kf01, s0);
    s1 = mfma_bf16(qf[0], kf10, s1);
    s1 = mfma_bf16(qf[1], kf11, s1);

    float corr[4];
#pragma unroll
    for (int r = 0; r < 4; r++) {
      int qrow = qrBase + grp * 4 + r;
      float v0 = (kt + l16 <= qrow) ? s0[r] * SCL : -1e30f;
      float v1 = (kt + 16 + l16 <= qrow) ? s1[r] * SCL : -1e30f;
      float mx = fmaxf(v0, v1);
#pragma unroll
      for (int off = 8; off >= 1; off >>= 1) mx = fmaxf(mx, __shfl_xor(mx, off));
      float mn = fmaxf(m[r], mx);
      float c0 = __expf(m[r] - mn);
      float p0 = __expf(v0 - mn), p1 = __expf(v1 - mn);
      float rs = p0 + p1;
#pragma unroll
      for (int off = 8; off >= 1; off >>= 1) rs += __shfl_xor(rs, off);
      l[r] = l[r] * c0 + rs;
      m[r] = mn;
      corr[r] = c0;
      Pl[w][(grp * 4 + r) * 40 + l16] = f2bf(p0);
      Pl[w][(grp * 4 + r) * 40 + 16 + l16] = f2bf(p1);
    }
#pragma unroll
    for (int dc = 0; dc < 4; dc++) {
#pragma unroll
      for (int r = 0; r < 4; r++) o[dc][r] *= corr[r];
    }
    bf16x8 pa =
        __builtin_bit_cast(bf16x8, *(const u32x4*)&Pl[w][l16 * 40 + grp * 8]);
#pragma unroll
    for (int dc = 0; dc < 4; dc++) o[dc] = mfma_bf16(pa, vf[dc], o[dc]);
  }

  const int b = bh >> 4, h = bh & 15;
#pragma unroll
  for (int r = 0; r < 4; r++) {
    float inv = 1.f / l[r];
    int qrow = qrBase + grp * 4 + r;
    size_t base = ((size_t)(b * T_ + qrow)) * HIDDEN + h * HD;
#pragma unroll
    for (int dc = 0; dc < 4; dc++)
      Ao[base + dc * 16 + l16] = f2bf(o[dc][r] * inv);
  }
}

extern "C" void kernel_launch(void* const* d_in, const int* in_sizes, int n_in,
                              void* d_out, int out_size, void* d_ws,
                              size_t ws_size, hipStream_t stream) {
  const float* data = (const float*)d_in[0];
  const float* qkvw = (const float*)d_in[1];
  const float* qkvb = (const float*)d_in[2];
  const float* outw = (const float*)d_in[3];
  const float* outb = (const float*)d_in[4];
  float* out = (float*)d_out;
  char* ws = (char*)d_ws;

  // workspace layout (bytes):
  unsigned short* dataBf = (unsigned short*)(ws);             // 16 MiB, reused as attnO
  unsigned short* qkvwBf = (unsigned short*)(ws + 16777216);  // 6 MiB
  unsigned short* outwBf = (unsigned short*)(ws + 23068672);  // 2 MiB
  unsigned short* Qb = (unsigned short*)(ws + 25165824);      // 16 MiB
  unsigned short* Kb = (unsigned short*)(ws + 41943040);      // 16 MiB
  unsigned short* Vtb = (unsigned short*)(ws + 58720256);     // 16 MiB
  unsigned short* attnO = dataBf;  // safe: dataBf dead after QKV GEMM

  cvt_bf16<<<2048, 256, 0, stream>>>(data, dataBf, (M_ROWS * HIDDEN) / 4);
  cvt_bf16<<<1024, 256, 0, stream>>>(qkvw, qkvwBf, (3 * HIDDEN * HIDDEN) / 4);
  cvt_bf16<<<512, 256, 0, stream>>>(outw, outwBf, (HIDDEN * HIDDEN) / 4);

  gemm_bt<0><<<dim3(24, 64), 256, 0, stream>>>(dataBf, qkvwBf, qkvb, Qb, Kb,
                                               Vtb, nullptr, M_ROWS, 3 * HIDDEN,
                                               HIDDEN);
  attn_kernel<<<dim3(64, 32), 256, 0, stream>>>(Qb, Kb, Vtb, attnO);
  gemm_bt<1><<<dim3(8, 64), 256, 0, stream>>>(attnO, outwBf, outb, nullptr,
                                              nullptr, nullptr, out, M_ROWS,
                                              HIDDEN, HIDDEN);
}

// Round 2
// 292.037 us; speedup vs baseline: 1.3500x; 1.3500x over previous
//
#include <hip/hip_runtime.h>
#include <hip/hip_bf16.h>
#include <stdint.h>

typedef __attribute__((ext_vector_type(8))) __bf16 bf16x8;
typedef __attribute__((ext_vector_type(4))) float f32x4;
typedef __attribute__((ext_vector_type(16))) float f32x16;
typedef __attribute__((ext_vector_type(4))) unsigned int u32x4;

#define HIDDEN 1024
#define HEADS 16
#define HD 64
#define NB 4
#define T_ 2048
#define M_ROWS (NB * T_)  // 8192

__device__ __forceinline__ unsigned short f2bf(float x) {
  unsigned u = __builtin_bit_cast(unsigned, x);
  u += 0x7fff + ((u >> 16) & 1);
  return (unsigned short)(u >> 16);
}

// pack two f32 -> two bf16 (round-half-up) in one u32 via v_perm
__device__ __forceinline__ unsigned pk2(float a, float b) {
  unsigned ua = __builtin_bit_cast(unsigned, a) + 0x8000u;
  unsigned ub = __builtin_bit_cast(unsigned, b) + 0x8000u;
  return __builtin_amdgcn_perm(ub, ua, 0x07060302);  // [ub.b3 ub.b2 ua.b3 ua.b2]
}

__device__ __forceinline__ f32x4 mfma16(bf16x8 a, bf16x8 b, f32x4 c) {
  return __builtin_amdgcn_mfma_f32_16x16x32_bf16(a, b, c, 0, 0, 0);
}
__device__ __forceinline__ f32x16 mfma32(bf16x8 a, bf16x8 b, f32x16 c) {
  return __builtin_amdgcn_mfma_f32_32x32x16_bf16(a, b, c, 0, 0, 0);
}

__device__ __forceinline__ void lds16(const void* g, void* l) {
  __builtin_amdgcn_global_load_lds(
      (const __attribute__((address_space(1))) unsigned int*)g,
      (__attribute__((address_space(3))) unsigned int*)l, 16, 0, 0);
}

__device__ __forceinline__ bf16x8 ldg8(const unsigned short* p) {
  return __builtin_bit_cast(bf16x8, *(const u32x4*)p);
}

// ---------------- f32 -> bf16 convert ----------------
__global__ void cvt_bf16(const float* __restrict__ in,
                         unsigned short* __restrict__ out, int n4) {
  int i = blockIdx.x * blockDim.x + threadIdx.x;
  int stride = gridDim.x * blockDim.x;
  for (; i < n4; i += stride) {
    float4 v = ((const float4*)in)[i];
    ushort4 o;
    o.x = f2bf(v.x); o.y = f2bf(v.y); o.z = f2bf(v.z); o.w = f2bf(v.w);
    ((ushort4*)out)[i] = o;
  }
}

// ---------------- 128x128 MFMA GEMM, C = A * B^T (+bias), m97 structure ----
template <int EPI>
__global__ __launch_bounds__(256) void gemm_bt(
    const unsigned short* __restrict__ A, const unsigned short* __restrict__ Bm,
    const float* __restrict__ bias, unsigned short* __restrict__ Qb,
    unsigned short* __restrict__ Kb, unsigned short* __restrict__ Vtb,
    float* __restrict__ Cf, int M, int N, int K) {
  __shared__ __align__(16) unsigned short Al[128 * 32];
  __shared__ __align__(16) unsigned short Bl[128 * 32];
  const int tid = threadIdx.x;
  const int w = tid >> 6, lane = tid & 63;
  const int l16 = lane & 15, grp = lane >> 4;
  const int brow0 = blockIdx.y * 128;
  const int bcol0 = blockIdx.x * 128;
  const int wrow = (w >> 1) * 64, wcol = (w & 1) * 64;

  f32x4 acc[4][4];
#pragma unroll
  for (int i = 0; i < 4; i++)
#pragma unroll
    for (int j = 0; j < 4; j++) acc[i][j] = (f32x4){0.f, 0.f, 0.f, 0.f};

  for (int k0 = 0; k0 < K; k0 += 32) {
    __syncthreads();
#pragma unroll
    for (int i = 0; i < 2; i++) {
      int off = (w * 2 + i) * 1024 + lane * 16;  // byte offset in 8KB tile
      int row = off >> 6;
      int cole = (off & 63) >> 1;
      lds16(A + (size_t)(brow0 + row) * K + k0 + cole,
            (char*)Al + (w * 2 + i) * 1024);
      lds16(Bm + (size_t)(bcol0 + row) * K + k0 + cole,
            (char*)Bl + (w * 2 + i) * 1024);
    }
    __syncthreads();
    bf16x8 av[4], bv[4];
#pragma unroll
    for (int m = 0; m < 4; m++)
      av[m] = __builtin_bit_cast(
          bf16x8, *(const u32x4*)&Al[(wrow + m * 16 + l16) * 32 + grp * 8]);
#pragma unroll
    for (int n = 0; n < 4; n++)
      bv[n] = __builtin_bit_cast(
          bf16x8, *(const u32x4*)&Bl[(wcol + n * 16 + l16) * 32 + grp * 8]);
#pragma unroll
    for (int m = 0; m < 4; m++)
#pragma unroll
      for (int n = 0; n < 4; n++) acc[m][n] = mfma16(av[m], bv[n], acc[m][n]);
  }

#pragma unroll
  for (int m = 0; m < 4; m++) {
#pragma unroll
    for (int n = 0; n < 4; n++) {
      int col = bcol0 + wcol + n * 16 + l16;
      int row0 = brow0 + wrow + m * 16 + grp * 4;
      float bs = bias[col];
      if (EPI == 0) {
        int part = col >> 10, rem = col & 1023;
        int h = rem >> 6, d = rem & 63;
#pragma unroll
        for (int r = 0; r < 4; r++) {
          int rw = row0 + r;
          int b = rw >> 11, t = rw & 2047;
          unsigned short val = f2bf(acc[m][n][r] + bs);
          size_t bh = (size_t)(b * 16 + h);
          if (part == 0)
            Qb[(bh * T_ + t) * HD + d] = val;
          else if (part == 1)
            Kb[(bh * T_ + t) * HD + d] = val;
          else
            Vtb[(bh * HD + d) * T_ + t] = val;
        }
      } else {
#pragma unroll
        for (int r = 0; r < 4; r++)
          Cf[(size_t)(row0 + r) * N + col] = acc[m][n][r] + bs;
      }
    }
  }
}

// ---------------- causal flash attention, swapped 32x32x16 ----------------
// 1 wave = 32 queries. grid = 1024 blocks x 256 thr (4 waves).
// Swapped QK^T: S^T = mfma(K, Q)  -> lane owns query col = lane&31.
// Swapped PV:   O^T = mfma(V^T, P^T) -> lane owns query col, rescale lane-local.
__global__ __launch_bounds__(256) void attn32(
    const unsigned short* __restrict__ Q, const unsigned short* __restrict__ K,
    const unsigned short* __restrict__ Vt, unsigned short* __restrict__ Ao) {
  const int i = blockIdx.x;
  const int xs = i & 7, kk = i >> 3;
  const int bh = xs + ((kk & 7) << 3);   // XCD slot = bh%8 -> K/V L2-resident
  const int tg = 15 - (kk >> 3);         // heavy tile-groups dispatched first
  const int w = threadIdx.x >> 6, lane = threadIdx.x & 63;
  const int l31 = lane & 31, hi = lane >> 5;
  const int qt = tg * 4 + w;             // 0..63 query tile (32 rows)
  const int qbase = qt * 32;
  const unsigned short* Qh = Q + (size_t)bh * T_ * HD;
  const unsigned short* Kh = K + (size_t)bh * T_ * HD;
  const unsigned short* Vh = Vt + (size_t)bh * HD * T_;

  bf16x8 qf[4];
#pragma unroll
  for (int st = 0; st < 4; st++)
    qf[st] = ldg8(&Qh[(size_t)(qbase + l31) * HD + st * 16 + hi * 8]);

  f32x16 o0 = {0.f}, o1 = {0.f};
#pragma unroll
  for (int r = 0; r < 16; r++) { o0[r] = 0.f; o1[r] = 0.f; }
  float m = -1e30f, l = 0.f;
  const float SCL2 = 0.18033688f;  // log2(e) / sqrt(64)

  for (int kc = 0; kc <= qt; kc++) {
    const int kt = kc * 32;
    bf16x8 kf0 = ldg8(&Kh[(size_t)(kt + l31) * HD + 0 + hi * 8]);
    bf16x8 kf1 = ldg8(&Kh[(size_t)(kt + l31) * HD + 16 + hi * 8]);
    bf16x8 kf2 = ldg8(&Kh[(size_t)(kt + l31) * HD + 32 + hi * 8]);
    bf16x8 kf3 = ldg8(&Kh[(size_t)(kt + l31) * HD + 48 + hi * 8]);
    bf16x8 vf00 = ldg8(&Vh[(size_t)l31 * T_ + kt + hi * 8]);
    bf16x8 vf01 = ldg8(&Vh[(size_t)l31 * T_ + kt + 16 + hi * 8]);
    bf16x8 vf10 = ldg8(&Vh[(size_t)(32 + l31) * T_ + kt + hi * 8]);
    bf16x8 vf11 = ldg8(&Vh[(size_t)(32 + l31) * T_ + kt + 16 + hi * 8]);

    f32x16 sa;
#pragma unroll
    for (int r = 0; r < 16; r++) sa[r] = 0.f;
    sa = mfma32(kf0, qf[0], sa);
    sa = mfma32(kf1, qf[1], sa);
    sa = mfma32(kf2, qf[2], sa);
    sa = mfma32(kf3, qf[3], sa);

    float sv[16];
    if (kc == qt) {  // diagonal chunk: mask key > query (both relative)
#pragma unroll
      for (int r = 0; r < 16; r++) {
        int key = (r & 3) + 8 * (r >> 2) + 4 * hi;
        sv[r] = (key <= l31) ? sa[r] * SCL2 : -1e30f;
      }
    } else {
#pragma unroll
      for (int r = 0; r < 16; r++) sv[r] = sa[r] * SCL2;
    }

    float mx = sv[0];
#pragma unroll
    for (int r = 1; r < 16; r++) mx = fmaxf(mx, sv[r]);
    mx = fmaxf(mx, __shfl_xor(mx, 32));

    if (mx > m + 10.f) {  // defer-max: skip rescale unless max grew a lot
      float c = exp2f(m - mx);
      l *= c;
#pragma unroll
      for (int r = 0; r < 16; r++) { o0[r] *= c; o1[r] *= c; }
      m = mx;
    }

    float pv[16];
    float rs = 0.f;
#pragma unroll
    for (int r = 0; r < 16; r++) {
      float p = exp2f(sv[r] - m);
      pv[r] = p;
      rs += p;
    }
    rs += __shfl_xor(rs, 32);
    l += rs;

    // pack P (16 f32) -> 8 u32 of bf16 pairs; redistribute across hi-halves
    unsigned wd[8], xd[8];
#pragma unroll
    for (int j = 0; j < 8; j++) wd[j] = pk2(pv[2 * j], pv[2 * j + 1]);
#pragma unroll
    for (int j = 0; j < 8; j++) xd[j] = (unsigned)__shfl_xor((int)wd[j], 32);
    // A/B-frag P^T: lane needs P[q][keys hi*8 + 0..7] (pa0: keys 0-15; pa1: 16-31)
    u32x4 pa0u, pa1u;
    pa0u.x = hi ? xd[2] : wd[0];
    pa0u.y = hi ? xd[3] : wd[1];
    pa0u.z = hi ? wd[2] : xd[0];
    pa0u.w = hi ? wd[3] : xd[1];
    pa1u.x = hi ? xd[6] : wd[4];
    pa1u.y = hi ? xd[7] : wd[5];
    pa1u.z = hi ? wd[6] : xd[4];
    pa1u.w = hi ? wd[7] : xd[5];
    bf16x8 pa0 = __builtin_bit_cast(bf16x8, pa0u);
    bf16x8 pa1 = __builtin_bit_cast(bf16x8, pa1u);

    o0 = mfma32(vf00, pa0, o0);
    o0 = mfma32(vf01, pa1, o0);
    o1 = mfma32(vf10, pa0, o1);
    o1 = mfma32(vf11, pa1, o1);
  }

  float inv = 1.0f / l;
  const int b = bh >> 4, h = bh & 15;
  const size_t base =
      ((size_t)b * T_ + qbase + l31) * HIDDEN + h * HD + hi * 4;
#pragma unroll
  for (int g = 0; g < 4; g++) {
    uint2 u;
    u.x = pk2(o0[4 * g] * inv, o0[4 * g + 1] * inv);
    u.y = pk2(o0[4 * g + 2] * inv, o0[4 * g + 3] * inv);
    *(uint2*)&Ao[base + g * 8] = u;
  }
#pragma unroll
  for (int g = 0; g < 4; g++) {
    uint2 u;
    u.x = pk2(o1[4 * g] * inv, o1[4 * g + 1] * inv);
    u.y = pk2(o1[4 * g + 2] * inv, o1[4 * g + 3] * inv);
    *(uint2*)&Ao[base + 32 + g * 8] = u;
  }
}

extern "C" void kernel_launch(void* const* d_in, const int* in_sizes, int n_in,
                              void* d_out, int out_size, void* d_ws,
                              size_t ws_size, hipStream_t stream) {
  const float* data = (const float*)d_in[0];
  const float* qkvw = (const float*)d_in[1];
  const float* qkvb = (const float*)d_in[2];
  const float* outw = (const float*)d_in[3];
  const float* outb = (const float*)d_in[4];
  float* out = (float*)d_out;
  char* ws = (char*)d_ws;

  unsigned short* dataBf = (unsigned short*)(ws);             // 16 MiB, reused as attnO
  unsigned short* qkvwBf = (unsigned short*)(ws + 16777216);  // 6 MiB
  unsigned short* outwBf = (unsigned short*)(ws + 23068672);  // 2 MiB
  unsigned short* Qb = (unsigned short*)(ws + 25165824);      // 16 MiB
  unsigned short* Kb = (unsigned short*)(ws + 41943040);      // 16 MiB
  unsigned short* Vtb = (unsigned short*)(ws + 58720256);     // 16 MiB
  unsigned short* attnO = dataBf;  // safe: dataBf dead after QKV GEMM

  cvt_bf16<<<2048, 256, 0, stream>>>(data, dataBf, (M_ROWS * HIDDEN) / 4);
  cvt_bf16<<<1024, 256, 0, stream>>>(qkvw, qkvwBf, (3 * HIDDEN * HIDDEN) / 4);
  cvt_bf16<<<512, 256, 0, stream>>>(outw, outwBf, (HIDDEN * HIDDEN) / 4);

  gemm_bt<0><<<dim3(24, 64), 256, 0, stream>>>(dataBf, qkvwBf, qkvb, Qb, Kb,
                                               Vtb, nullptr, M_ROWS, 3 * HIDDEN,
                                               HIDDEN);
  attn32<<<1024, 256, 0, stream>>>(Qb, Kb, Vtb, attnO);
  gemm_bt<1><<<dim3(8, 64), 256, 0, stream>>>(attnO, outwBf, outb, nullptr,
                                              nullptr, nullptr, out, M_ROWS,
                                              HIDDEN, HIDDEN);
}

// Round 6
// 279.116 us; speedup vs baseline: 1.4125x; 1.0463x over previous
//
#include <hip/hip_runtime.h>
#include <hip/hip_bf16.h>
#include <stdint.h>

typedef __attribute__((ext_vector_type(8))) __bf16 bf16x8;
typedef __attribute__((ext_vector_type(4))) float f32x4;
typedef __attribute__((ext_vector_type(16))) float f32x16;
typedef __attribute__((ext_vector_type(4))) unsigned int u32x4;

#define HIDDEN 1024
#define HEADS 16
#define HD 64
#define NB 4
#define T_ 2048
#define M_ROWS (NB * T_)  // 8192
#define SCL2 0.18033688f  // log2(e)/sqrt(64), applied in-kernel (round-1 proven)

__device__ __forceinline__ unsigned short f2bf(float x) {
  unsigned u = __builtin_bit_cast(unsigned, x);
  u += 0x7fff + ((u >> 16) & 1);
  return (unsigned short)(u >> 16);
}

// pack two f32 -> two bf16 (round-half-up) in one u32 via v_perm
__device__ __forceinline__ unsigned pk2(float a, float b) {
  unsigned ua = __builtin_bit_cast(unsigned, a) + 0x8000u;
  unsigned ub = __builtin_bit_cast(unsigned, b) + 0x8000u;
  return __builtin_amdgcn_perm(ub, ua, 0x07060302);
}

__device__ __forceinline__ f32x4 mfma16(bf16x8 a, bf16x8 b, f32x4 c) {
  return __builtin_amdgcn_mfma_f32_16x16x32_bf16(a, b, c, 0, 0, 0);
}
__device__ __forceinline__ f32x16 mfma32(bf16x8 a, bf16x8 b, f32x16 c) {
  return __builtin_amdgcn_mfma_f32_32x32x16_bf16(a, b, c, 0, 0, 0);
}

__device__ __forceinline__ void lds16(const void* g, void* l) {
  __builtin_amdgcn_global_load_lds(
      (const __attribute__((address_space(1))) unsigned int*)g,
      (__attribute__((address_space(3))) unsigned int*)l, 16, 0, 0);
}

__device__ __forceinline__ bf16x8 ldg8(const unsigned short* p) {
  return __builtin_bit_cast(bf16x8, *(const u32x4*)p);
}

// ---------------- f32 -> bf16 convert ----------------
__global__ void cvt_bf16(const float* __restrict__ in,
                         unsigned short* __restrict__ out, int n4) {
  int i = blockIdx.x * blockDim.x + threadIdx.x;
  int stride = gridDim.x * blockDim.x;
  for (; i < n4; i += stride) {
    float4 v = ((const float4*)in)[i];
    ushort4 o;
    o.x = f2bf(v.x); o.y = f2bf(v.y); o.z = f2bf(v.z); o.w = f2bf(v.w);
    ((ushort4*)out)[i] = o;
  }
}

// ---------------- 128x128 MFMA GEMM, C = A * B^T (+bias), m97 structure ----
template <int EPI>
__global__ __launch_bounds__(256) void gemm_bt(
    const unsigned short* __restrict__ A, const unsigned short* __restrict__ Bm,
    const float* __restrict__ bias, unsigned short* __restrict__ Qb,
    unsigned short* __restrict__ Kb, unsigned short* __restrict__ Vtb,
    float* __restrict__ Cf, int M, int N, int K) {
  __shared__ __align__(16) unsigned short Al[128 * 32];
  __shared__ __align__(16) unsigned short Bl[128 * 32];
  const int tid = threadIdx.x;
  const int w = tid >> 6, lane = tid & 63;
  const int l16 = lane & 15, grp = lane >> 4;
  const int brow0 = blockIdx.y * 128;
  const int bcol0 = blockIdx.x * 128;
  const int wrow = (w >> 1) * 64, wcol = (w & 1) * 64;

  f32x4 acc[4][4];
#pragma unroll
  for (int i = 0; i < 4; i++)
#pragma unroll
    for (int j = 0; j < 4; j++) acc[i][j] = (f32x4){0.f, 0.f, 0.f, 0.f};

  for (int k0 = 0; k0 < K; k0 += 32) {
    __syncthreads();
#pragma unroll
    for (int i = 0; i < 2; i++) {
      int off = (w * 2 + i) * 1024 + lane * 16;  // byte offset in 8KB tile
      int row = off >> 6;
      int cole = (off & 63) >> 1;
      lds16(A + (size_t)(brow0 + row) * K + k0 + cole,
            (char*)Al + (w * 2 + i) * 1024);
      lds16(Bm + (size_t)(bcol0 + row) * K + k0 + cole,
            (char*)Bl + (w * 2 + i) * 1024);
    }
    __syncthreads();
    bf16x8 av[4], bv[4];
#pragma unroll
    for (int m = 0; m < 4; m++)
      av[m] = __builtin_bit_cast(
          bf16x8, *(const u32x4*)&Al[(wrow + m * 16 + l16) * 32 + grp * 8]);
#pragma unroll
    for (int n = 0; n < 4; n++)
      bv[n] = __builtin_bit_cast(
          bf16x8, *(const u32x4*)&Bl[(wcol + n * 16 + l16) * 32 + grp * 8]);
#pragma unroll
    for (int m = 0; m < 4; m++)
#pragma unroll
      for (int n = 0; n < 4; n++) acc[m][n] = mfma16(av[m], bv[n], acc[m][n]);
  }

#pragma unroll
  for (int m = 0; m < 4; m++) {
#pragma unroll
    for (int n = 0; n < 4; n++) {
      int col = bcol0 + wcol + n * 16 + l16;
      int row0 = brow0 + wrow + m * 16 + grp * 4;
      float bs = bias[col];
      if (EPI == 0) {
        int part = col >> 10, rem = col & 1023;
        int h = rem >> 6, d = rem & 63;
#pragma unroll
        for (int r = 0; r < 4; r++) {
          int rw = row0 + r;
          int b = rw >> 11, t = rw & 2047;
          unsigned short val = f2bf(acc[m][n][r] + bs);
          size_t bh = (size_t)(b * 16 + h);
          if (part == 0)
            Qb[(bh * T_ + t) * HD + d] = val;
          else if (part == 1)
            Kb[(bh * T_ + t) * HD + d] = val;
          else
            Vtb[(bh * HD + d) * T_ + t] = val;
        }
      } else {
#pragma unroll
        for (int r = 0; r < 4; r++)
          Cf[(size_t)(row0 + r) * N + col] = acc[m][n][r] + bs;
      }
    }
  }
}

// ---------------- causal flash attention, swapped 32x32x16 ----------------
// 1024 blocks x 128 thr (2 waves). Wave handles qt pair (p, 63-p): 65 chunks
// each -> perfect balance. K/V reg-double-buffered prefetch. ALL cross-lane
// ops are the round-1-PROVEN __shfl_xor(.,32) forms; no permlane anywhere
// (permlane self-swap suspected miscompile: identical 0.76 absmax across two
// equivalent P-wirings in r2/r4).

#define PF(KF, VF, KC)                                          \
  do {                                                          \
    int kt_ = (KC) * 32;                                        \
    KF[0] = ldg8(&Kh[(size_t)(kt_ + l31) * HD + hi * 8]);       \
    KF[1] = ldg8(&Kh[(size_t)(kt_ + l31) * HD + 16 + hi * 8]);  \
    KF[2] = ldg8(&Kh[(size_t)(kt_ + l31) * HD + 32 + hi * 8]);  \
    KF[3] = ldg8(&Kh[(size_t)(kt_ + l31) * HD + 48 + hi * 8]);  \
    VF[0] = ldg8(&Vh[(size_t)l31 * T_ + kt_ + hi * 8]);         \
    VF[1] = ldg8(&Vh[(size_t)l31 * T_ + kt_ + 16 + hi * 8]);    \
    VF[2] = ldg8(&Vh[(size_t)(32 + l31) * T_ + kt_ + hi * 8]);  \
    VF[3] = ldg8(&Vh[(size_t)(32 + l31) * T_ + kt_ + 16 + hi * 8]); \
  } while (0)

#define CHUNK(KF, VF, MASKED)                                                \
  do {                                                                       \
    f32x16 sa;                                                               \
    _Pragma("unroll") for (int r = 0; r < 16; r++) sa[r] = 0.f;              \
    sa = mfma32(KF[0], qf[0], sa);                                           \
    sa = mfma32(KF[1], qf[1], sa);                                           \
    sa = mfma32(KF[2], qf[2], sa);                                           \
    sa = mfma32(KF[3], qf[3], sa);                                           \
    float sv[16];                                                            \
    _Pragma("unroll") for (int r = 0; r < 16; r++) {                         \
      sv[r] = sa[r] * SCL2;                                                  \
      if (MASKED) {                                                          \
        int key = (r & 3) + 8 * (r >> 2) + 4 * hi;                           \
        if (key > l31) sv[r] = -1e30f;                                       \
      }                                                                      \
    }                                                                        \
    float mx = sv[0];                                                        \
    _Pragma("unroll") for (int r = 1; r < 16; r++) mx = fmaxf(mx, sv[r]);    \
    mx = fmaxf(mx, __shfl_xor(mx, 32));                                      \
    if (mx > rm + 10.f) { /* defer-max */                                    \
      float c = exp2f(rm - mx);                                              \
      rl *= c;                                                               \
      _Pragma("unroll") for (int r = 0; r < 16; r++) {                       \
        o0[r] *= c;                                                          \
        o1[r] *= c;                                                          \
      }                                                                      \
      rm = mx;                                                               \
    }                                                                        \
    float rs = 0.f, pv[16];                                                  \
    _Pragma("unroll") for (int r = 0; r < 16; r++) {                         \
      pv[r] = exp2f(sv[r] - rm);                                             \
      rs += pv[r];                                                           \
    }                                                                        \
    rs += __shfl_xor(rs, 32);                                                \
    rl += rs;                                                                \
    unsigned wd[8], xd[8];                                                   \
    _Pragma("unroll") for (int j = 0; j < 8; j++)                            \
        wd[j] = pk2(pv[2 * j], pv[2 * j + 1]);                               \
    _Pragma("unroll") for (int j = 0; j < 8; j++)                            \
        xd[j] = (unsigned)__shfl_xor((int)wd[j], 32);                        \
    u32x4 pa0u, pa1u;                                                        \
    pa0u.x = hi ? xd[2] : wd[0];                                             \
    pa0u.y = hi ? xd[3] : wd[1];                                             \
    pa0u.z = hi ? wd[2] : xd[0];                                             \
    pa0u.w = hi ? wd[3] : xd[1];                                             \
    pa1u.x = hi ? xd[6] : wd[4];                                             \
    pa1u.y = hi ? xd[7] : wd[5];                                             \
    pa1u.z = hi ? wd[6] : xd[4];                                             \
    pa1u.w = hi ? wd[7] : xd[5];                                             \
    bf16x8 pa0 = __builtin_bit_cast(bf16x8, pa0u);                           \
    bf16x8 pa1 = __builtin_bit_cast(bf16x8, pa1u);                           \
    o0 = mfma32(VF[0], pa0, o0);                                             \
    o0 = mfma32(VF[1], pa1, o0);                                             \
    o1 = mfma32(VF[2], pa0, o1);                                             \
    o1 = mfma32(VF[3], pa1, o1);                                             \
  } while (0)

#define TILE(QT)                                                           \
  do {                                                                     \
    const int qt = (QT);                                                   \
    const int qbase = qt * 32;                                             \
    _Pragma("unroll") for (int st = 0; st < 4; st++) qf[st] =              \
        ldg8(&Qh[(size_t)(qbase + l31) * HD + st * 16 + hi * 8]);          \
    _Pragma("unroll") for (int r = 0; r < 16; r++) {                       \
      o0[r] = 0.f;                                                         \
      o1[r] = 0.f;                                                         \
    }                                                                      \
    rm = -1e30f;                                                           \
    rl = 0.f;                                                              \
    PF(kA, vA, 0);                                                         \
    int kc = 0;                                                            \
    while (kc + 2 <= qt) {                                                 \
      PF(kB, vB, kc + 1);                                                  \
      CHUNK(kA, vA, 0);                                                    \
      PF(kA, vA, kc + 2);                                                  \
      CHUNK(kB, vB, 0);                                                    \
      kc += 2;                                                             \
    }                                                                      \
    if (kc < qt) {                                                         \
      PF(kB, vB, kc + 1);                                                  \
      CHUNK(kA, vA, 0);                                                    \
      CHUNK(kB, vB, 1);                                                    \
    } else {                                                               \
      CHUNK(kA, vA, 1);                                                    \
    }                                                                      \
    float inv = 1.f / rl;                                                  \
    const size_t base =                                                    \
        ((size_t)b_ * T_ + qbase + l31) * HIDDEN + h_ * HD + hi * 4;       \
    _Pragma("unroll") for (int g = 0; g < 4; g++) {                        \
      uint2 u;                                                             \
      u.x = pk2(o0[4 * g] * inv, o0[4 * g + 1] * inv);                     \
      u.y = pk2(o0[4 * g + 2] * inv, o0[4 * g + 3] * inv);                 \
      *(uint2*)&Ao[base + g * 8] = u;                                      \
    }                                                                      \
    _Pragma("unroll") for (int g = 0; g < 4; g++) {                        \
      uint2 u;                                                             \
      u.x = pk2(o1[4 * g] * inv, o1[4 * g + 1] * inv);                     \
      u.y = pk2(o1[4 * g + 2] * inv, o1[4 * g + 3] * inv);                 \
      *(uint2*)&Ao[base + 32 + g * 8] = u;                                 \
    }                                                                      \
  } while (0)

__global__ __launch_bounds__(128, 2) void attn32(
    const unsigned short* __restrict__ Q, const unsigned short* __restrict__ K,
    const unsigned short* __restrict__ Vt, unsigned short* __restrict__ Ao) {
  const int i = blockIdx.x;
  const int xcd = i & 7, sub = i >> 3;          // sub 0..127
  const int bh = xcd + 8 * (sub >> 4);          // 8 heads per XCD: K/V L2-fit
  const int wv = threadIdx.x >> 6, lane = threadIdx.x & 63;
  const int l31 = lane & 31, hi = lane >> 5;
  const int p = (sub & 15) * 2 + wv;            // 0..31: tiles (p, 63-p)
  const unsigned short* Qh = Q + (size_t)bh * T_ * HD;
  const unsigned short* Kh = K + (size_t)bh * T_ * HD;
  const unsigned short* Vh = Vt + (size_t)bh * HD * T_;
  const int b_ = bh >> 4, h_ = bh & 15;

  bf16x8 qf[4], kA[4], vA[4], kB[4], vB[4];
  f32x16 o0, o1;
  float rm, rl;

  TILE(p);
  TILE(63 - p);
}

extern "C" void kernel_launch(void* const* d_in, const int* in_sizes, int n_in,
                              void* d_out, int out_size, void* d_ws,
                              size_t ws_size, hipStream_t stream) {
  const float* data = (const float*)d_in[0];
  const float* qkvw = (const float*)d_in[1];
  const float* qkvb = (const float*)d_in[2];
  const float* outw = (const float*)d_in[3];
  const float* outb = (const float*)d_in[4];
  float* out = (float*)d_out;
  char* ws = (char*)d_ws;

  unsigned short* dataBf = (unsigned short*)(ws);             // 16 MiB, reused as attnO
  unsigned short* qkvwBf = (unsigned short*)(ws + 16777216);  // 6 MiB
  unsigned short* outwBf = (unsigned short*)(ws + 23068672);  // 2 MiB
  unsigned short* Qb = (unsigned short*)(ws + 25165824);      // 16 MiB
  unsigned short* Kb = (unsigned short*)(ws + 41943040);      // 16 MiB
  unsigned short* Vtb = (unsigned short*)(ws + 58720256);     // 16 MiB
  unsigned short* attnO = dataBf;  // safe: dataBf dead after QKV GEMM

  cvt_bf16<<<2048, 256, 0, stream>>>(data, dataBf, (M_ROWS * HIDDEN) / 4);
  cvt_bf16<<<1024, 256, 0, stream>>>(qkvw, qkvwBf, (3 * HIDDEN * HIDDEN) / 4);
  cvt_bf16<<<512, 256, 0, stream>>>(outw, outwBf, (HIDDEN * HIDDEN) / 4);

  gemm_bt<0><<<dim3(24, 64), 256, 0, stream>>>(dataBf, qkvwBf, qkvb, Qb, Kb,
                                               Vtb, nullptr, M_ROWS, 3 * HIDDEN,
                                               HIDDEN);
  attn32<<<1024, 128, 0, stream>>>(Qb, Kb, Vtb, attnO);
  gemm_bt<1><<<dim3(8, 64), 256, 0, stream>>>(attnO, outwBf, outb, nullptr,
                                              nullptr, nullptr, out, M_ROWS,
                                              HIDDEN, HIDDEN);
}